// Round 5
// baseline (2426.406 us; speedup 1.0000x reference)
//
#include <hip/hip_runtime.h>
#include <hip/hip_bf16.h>

#define NPTS 200000
#define CIN 64
#define COUT 64
#define KVOL 27
#define NPAIRS 100000
#define GROUPS_PER_K (NPAIRS / 16)                                               // 6250
#define GROUPS_PER_BLOCK 64
#define CHUNKS_PER_K ((GROUPS_PER_K + GROUPS_PER_BLOCK - 1) / GROUPS_PER_BLOCK)  // 98
#define BN_EPS 1e-5f

typedef __attribute__((ext_vector_type(8))) short short8;   // 8 bf16 bits (4 VGPRs)
typedef __attribute__((ext_vector_type(4))) float f32x4;
typedef __attribute__((ext_vector_type(2))) float f32x2;

__device__ inline ushort f2bf(float x) {
    union { __hip_bfloat16 h; ushort u; } cv;
    cv.h = __float2bfloat16(x);   // RNE
    return cv.u;
}

// Packed 2xfp32 atomic add (halves the TCC atomic-op count vs scalar).
__device__ inline void atomic_pk_add(float* addr, f32x2 v) {
#if __has_builtin(__builtin_amdgcn_flat_atomic_fadd_v2f32)
    __builtin_amdgcn_flat_atomic_fadd_v2f32((f32x2*)addr, v);
#elif __has_builtin(__builtin_amdgcn_global_atomic_fadd_v2f32)
    typedef __attribute__((address_space(1))) f32x2 gv2f;
    __builtin_amdgcn_global_atomic_fadd_v2f32((gv2f*)(unsigned long long)addr, v);
#else
    unsafeAtomicAdd(addr, v.x);
    unsafeAtomicAdd(addr + 1, v.y);
#endif
}

// Per 16-pair group, one wave computes contrib^T[64 couts][16 pairs] via 8 MFMAs
// with SWAPPED operands (A = W^T tile, B = feats^T), so each lane ends up with
// 4 CONSECUTIVE couts of ONE pair per nt-tile -> 2 packed atomics per tile.
//  A[m=lane&15][k=q*8+e] = W[k][cout=nt*16+m]      (same fragment as before, new role)
//  B[k=q*8+e][j=lane&15] = feats[row_j][k]         (same gather as before, new role)
//  D[row=cout_local=q*4+r][col=pair=m]             (verified C/D layout)
__global__ __launch_bounds__(256) void conv_scatter_kernel(
    const float* __restrict__ feats,      // fp32 [NPTS][CIN]
    const float* __restrict__ wk,         // fp32 [KVOL][CIN][COUT]
    const int* __restrict__ in_map,       // [KVOL][NPAIRS]
    const int* __restrict__ out_map,      // [KVOL][NPAIRS]
    float* __restrict__ accum)            // [NPTS][COUT] fp32
{
    const int koff  = blockIdx.x / CHUNKS_PER_K;
    const int chunk = blockIdx.x % CHUNKS_PER_K;
    const int lane  = threadIdx.x & 63;
    const int wave  = threadIdx.x >> 6;
    const int m     = lane & 15;
    const int q     = lane >> 4;

    // W[koff] fragments (fp32 -> bf16), once per block (amortized over 64 groups).
    // wfrag[h][nt][e] = W[koff][h*32 + q*8 + e][nt*16 + m]  == A-operand W^T tile.
    short8 wfrag[2][4];
    const float* wbase = wk + koff * (CIN * COUT);
    #pragma unroll
    for (int h = 0; h < 2; ++h) {
        #pragma unroll
        for (int nt = 0; nt < 4; ++nt) {
            #pragma unroll
            for (int e = 0; e < 8; ++e) {
                const int kin = h * 32 + q * 8 + e;
                wfrag[h][nt][e] = (short)f2bf(wbase[kin * COUT + nt * 16 + m]);
            }
        }
    }

    const int* imap = in_map + koff * NPAIRS;
    const int* omap = out_map + koff * NPAIRS;

    #pragma unroll 1
    for (int it = 0; it < GROUPS_PER_BLOCK / 4; ++it) {
        const int g = chunk * GROUPS_PER_BLOCK + it * 4 + wave;
        if (g >= GROUPS_PER_K) break;
        const int base = g * 16;

        // Gather B-operand: lane m owns pair m's input row.
        const int row = imap[base + m];
        const float* fr = feats + (size_t)row * CIN + q * 8;
        const f32x4 f00 = *(const f32x4*)(fr);
        const f32x4 f01 = *(const f32x4*)(fr + 4);
        const f32x4 f10 = *(const f32x4*)(fr + 32);
        const f32x4 f11 = *(const f32x4*)(fr + 36);

        short8 b0, b1;
        #pragma unroll
        for (int e = 0; e < 4; ++e) {
            b0[e]     = (short)f2bf(f00[e]);
            b0[e + 4] = (short)f2bf(f01[e]);
            b1[e]     = (short)f2bf(f10[e]);
            b1[e + 4] = (short)f2bf(f11[e]);
        }

        f32x4 acc[4];
        #pragma unroll
        for (int nt = 0; nt < 4; ++nt) acc[nt] = (f32x4){0.f, 0.f, 0.f, 0.f};
        #pragma unroll
        for (int nt = 0; nt < 4; ++nt) {
            acc[nt] = __builtin_amdgcn_mfma_f32_16x16x32_bf16(wfrag[0][nt], b0, acc[nt], 0, 0, 0);
            acc[nt] = __builtin_amdgcn_mfma_f32_16x16x32_bf16(wfrag[1][nt], b1, acc[nt], 0, 0, 0);
        }

        // Scatter: lane (q,m) holds couts nt*16 + q*4 + [0..3] of pair m.
        const int orow = omap[base + m];
        float* obase = accum + (size_t)orow * COUT + q * 4;
        #pragma unroll
        for (int nt = 0; nt < 4; ++nt) {
            atomic_pk_add(obase + nt * 16,     (f32x2){acc[nt][0], acc[nt][1]});
            atomic_pk_add(obase + nt * 16 + 2, (f32x2){acc[nt][2], acc[nt][3]});
        }
    }
}

// BN (inference-folded) + ReLU; fp32 accum -> fp32 out.
__global__ __launch_bounds__(256) void bn_relu_kernel(
    const float* __restrict__ accum,
    const float* __restrict__ gamma,
    const float* __restrict__ beta,
    const float* __restrict__ rmean,
    const float* __restrict__ rvar,
    float* __restrict__ out)
{
    __shared__ float s_scale[COUT];
    __shared__ float s_bias[COUT];
    if (threadIdx.x < COUT) {
        const int c = threadIdx.x;
        const float sc = gamma[c] * rsqrtf(rvar[c] + BN_EPS);
        s_scale[c] = sc;
        s_bias[c]  = beta[c] - rmean[c] * sc;
    }
    __syncthreads();

    const int idx = (blockIdx.x * 256 + threadIdx.x) * 4;
    if (idx < NPTS * COUT) {
        const f32x4 v = *(const f32x4*)(accum + idx);
        const int c0 = idx & (COUT - 1);   // 4 | COUT, so c0..c0+3 stay in-row
        f32x4 o;
        #pragma unroll
        for (int e = 0; e < 4; ++e) {
            o[e] = fmaxf(v[e] * s_scale[c0 + e] + s_bias[c0 + e], 0.f);
        }
        *(f32x4*)(out + idx) = o;
    }
}

extern "C" void kernel_launch(void* const* d_in, const int* in_sizes, int n_in,
                              void* d_out, int out_size, void* d_ws, size_t ws_size,
                              hipStream_t stream) {
    const float* feats = (const float*)d_in[0];
    const float* wk    = (const float*)d_in[1];
    const float* gamma = (const float*)d_in[2];
    const float* beta  = (const float*)d_in[3];
    const float* rmean = (const float*)d_in[4];
    const float* rvar  = (const float*)d_in[5];
    const int* imap    = (const int*)d_in[6];
    const int* omap    = (const int*)d_in[7];
    float* out         = (float*)d_out;
    float* accum       = (float*)d_ws;   // 200000*64*4 = 51.2 MB scratch

    hipMemsetAsync(accum, 0, (size_t)NPTS * COUT * sizeof(float), stream);

    conv_scatter_kernel<<<KVOL * CHUNKS_PER_K, 256, 0, stream>>>(feats, wk, imap, omap, accum);

    bn_relu_kernel<<<(NPTS * COUT / 4 + 255) / 256, 256, 0, stream>>>(
        accum, gamma, beta, rmean, rvar, out);
}

// Round 6
// 1419.328 us; speedup vs baseline: 1.7095x; 1.7095x over previous
//
#include <hip/hip_runtime.h>
#include <hip/hip_bf16.h>

#define NPTS 200000
#define CIN 64
#define COUT 64
#define KVOL 27
#define NPAIRS 100000
#define NTOT (KVOL * NPAIRS)          // 2,700,000 pairs
#define RB 128                        // output rows per bucket
#define NB ((NPTS + RB - 1) / RB)     // 1563 buckets
#define NSEG (NB * KVOL)              // 42201 (bucket,k) segments
#define NSUB 8                        // sub-counters per segment (decontend atomics)
#define SCAN_BLOCKS ((NSEG + 255) / 256)  // 165
#define LIST_CAP (NTOT + NSEG * 15)   // worst-case pad-to-16
#define BN_EPS 1e-5f

typedef __attribute__((ext_vector_type(8))) short short8;
typedef __attribute__((ext_vector_type(4))) float f32x4;

__device__ inline ushort f2bf(float x) {
    union { __hip_bfloat16 h; ushort u; } cv;
    cv.h = __float2bfloat16(x);
    return cv.u;
}

// Native fire-and-forget LDS fp32 add. Plain atomicAdd(float*) on LDS is a CAS
// retry loop (R3's bottleneck); ds_add_f32 is atomic at the LDS banks with no
// result wait. addr = LDS byte offset (low 32 bits of the flat pointer).
__device__ __forceinline__ void lds_add_f32(unsigned addr, float v) {
    asm volatile("ds_add_f32 %0, %1" : : "v"(addr), "v"(v));
}

// ---- Phase A ----------------------------------------------------------------

// Histogram pairs into (bucket,k) segments, 8-way sub-counters to cut
// same-address TCC atomic serialization.
__global__ __launch_bounds__(256) void hist_kernel(
    const int* __restrict__ out_map, int* __restrict__ cnt8)
{
    const int t = blockIdx.x * 256 + threadIdx.x;
    if (t >= NTOT) return;
    const int k = t / NPAIRS;
    const int o = out_map[t];
    atomicAdd(&cnt8[((o >> 7) * KVOL + k) * NSUB + (t & (NSUB - 1))], 1);
}

// Exclusive scan of pad16(segment totals); also writes raw totals.
__global__ __launch_bounds__(256) void scan_block_kernel(
    const int* __restrict__ cnt8, int* __restrict__ off,
    int* __restrict__ cnt_tot, int* __restrict__ bsum)
{
    __shared__ int s[256];
    const int tid = threadIdx.x;
    const int idx = blockIdx.x * 256 + tid;
    int tot = 0;
    if (idx < NSEG) {
        #pragma unroll
        for (int j = 0; j < NSUB; ++j) tot += cnt8[idx * NSUB + j];
        cnt_tot[idx] = tot;
    }
    const int v = (idx < NSEG) ? ((tot + 15) & ~15) : 0;
    s[tid] = v;
    __syncthreads();
    for (int d = 1; d < 256; d <<= 1) {
        const int t = (tid >= d) ? s[tid - d] : 0;
        __syncthreads();
        s[tid] += t;
        __syncthreads();
    }
    if (idx < NSEG) off[idx] = s[tid] - v;
    if (tid == 255) bsum[blockIdx.x] = s[255];
}

__global__ __launch_bounds__(256) void scan_bsum_kernel(int* __restrict__ bsum)
{
    __shared__ int s[256];
    const int tid = threadIdx.x;
    const int v = (tid < SCAN_BLOCKS) ? bsum[tid] : 0;
    s[tid] = v;
    __syncthreads();
    for (int d = 1; d < 256; d <<= 1) {
        const int t = (tid >= d) ? s[tid - d] : 0;
        __syncthreads();
        s[tid] += t;
        __syncthreads();
    }
    if (tid < SCAN_BLOCKS) bsum[tid] = s[tid] - v;  // exclusive
}

// Finalize off (add block sums) and expand per-sub-counter offsets.
__global__ __launch_bounds__(256) void add_offsets_kernel(
    int* __restrict__ off, const int* __restrict__ bsum,
    const int* __restrict__ cnt8, int* __restrict__ off8)
{
    const int idx = blockIdx.x * 256 + threadIdx.x;
    if (idx >= NSEG) return;
    int o = off[idx] + bsum[blockIdx.x];
    off[idx] = o;
    #pragma unroll
    for (int j = 0; j < NSUB; ++j) {
        off8[idx * NSUB + j] = o;
        o += cnt8[idx * NSUB + j];
    }
}

// Scatter pair records into segment lists (no sentinels; validity from counts).
// rec = in_row (18b) | local_out_row (7b) << 18.
__global__ __launch_bounds__(256) void fill_kernel(
    const int* __restrict__ in_map, const int* __restrict__ out_map,
    const int* __restrict__ off8, int* __restrict__ cur8, int* __restrict__ list)
{
    const int t = blockIdx.x * 256 + threadIdx.x;
    if (t >= NTOT) return;
    const int k = t / NPAIRS;
    const int o = out_map[t];
    const int sub = ((o >> 7) * KVOL + k) * NSUB + (t & (NSUB - 1));
    const int slot = atomicAdd(&cur8[sub], 1);
    list[off8[sub] + slot] = in_map[t] | ((o & 127) << 18);
}

// Repack weights fp32 -> bf16 in lane-fragment order:
// wpack[((k*8 + h*4 + nt)*64 + lane)*8 + e] = W[k][h*32 + (lane>>4)*8 + e][nt*16 + (lane&15)]
__global__ __launch_bounds__(256) void repack_w_kernel(
    const float* __restrict__ wk, ushort* __restrict__ wpack)
{
    const int idx = blockIdx.x * 256 + threadIdx.x;
    if (idx >= KVOL * 8 * 64 * 8) return;
    const int e    = idx & 7;
    const int lane = (idx >> 3) & 63;
    const int f    = (idx >> 9) & 7;   // h*4 + nt
    const int k    = idx >> 12;
    const int h = f >> 2, nt = f & 3;
    const int q = lane >> 4, m = lane & 15;
    const int kin = h * 32 + q * 8 + e;
    wpack[idx] = f2bf(wk[k * (CIN * COUT) + kin * COUT + nt * 16 + m]);
}

// ---- Phase B: bucketed conv + native LDS accumulate + fused BN/ReLU --------
__global__ __launch_bounds__(256) void conv_bucket_kernel(
    const float* __restrict__ feats,    // fp32 [NPTS][CIN]
    const ushort* __restrict__ wpack,   // bf16 fragments
    const int* __restrict__ off,        // [NSEG] padded exclusive offsets
    const int* __restrict__ cnt_tot,    // [NSEG] raw counts
    const int* __restrict__ list,       // records
    const float* __restrict__ gamma, const float* __restrict__ beta,
    const float* __restrict__ rmean, const float* __restrict__ rvar,
    float* __restrict__ out)            // fp32 [NPTS][COUT]
{
    __shared__ float sacc[RB * COUT];   // 32 KB, XOR-bit4 swizzled by row parity
    const unsigned lds_base = (unsigned)(size_t)(void*)sacc;  // LDS byte offset

    const int b    = blockIdx.x;
    const int tid  = threadIdx.x;
    const int lane = tid & 63;
    const int wave = tid >> 6;
    const int m    = lane & 15;
    const int q    = lane >> 4;

    // Zero the LDS accumulator.
    {
        f32x4* z = (f32x4*)sacc;
        #pragma unroll
        for (int i = 0; i < (RB * COUT / 4) / 256; ++i)
            z[tid + i * 256] = (f32x4){0.f, 0.f, 0.f, 0.f};
    }
    __syncthreads();

    #pragma unroll 1
    for (int k = 0; k < KVOL; ++k) {
        const int seg = b * KVOL + k;
        const int s0  = off[seg];
        const int n   = cnt_tot[seg];
        const int ng  = (n + 15) >> 4;
        if (ng == 0) continue;

        // B fragments for this k: 8 x 16B vector loads from wpack.
        short8 bfrag[2][4];
        #pragma unroll
        for (int f = 0; f < 8; ++f)
            bfrag[f >> 2][f & 3] =
                *(const short8*)(wpack + ((size_t)(k * 8 + f) * 64 + lane) * 8);

        #pragma unroll 1
        for (int g = wave; g < ng; g += 4) {
            const int base = s0 + g * 16;
            const int rem  = n - g * 16;              // >= 1; >=16 for full groups
            const int rec  = (m < rem) ? list[base + m] : 0;
            const int row  = rec & 0x3FFFF;

            // Gather A (fp32 -> bf16): lane m owns pair slot base+m.
            const float* fr = feats + (size_t)row * CIN + q * 8;
            const f32x4 f00 = *(const f32x4*)(fr);
            const f32x4 f01 = *(const f32x4*)(fr + 4);
            const f32x4 f10 = *(const f32x4*)(fr + 32);
            const f32x4 f11 = *(const f32x4*)(fr + 36);
            short8 a0, a1;
            #pragma unroll
            for (int e = 0; e < 4; ++e) {
                a0[e]     = (short)f2bf(f00[e]);
                a0[e + 4] = (short)f2bf(f01[e]);
                a1[e]     = (short)f2bf(f10[e]);
                a1[e + 4] = (short)f2bf(f11[e]);
            }

            f32x4 acc[4];
            #pragma unroll
            for (int nt = 0; nt < 4; ++nt) acc[nt] = (f32x4){0.f, 0.f, 0.f, 0.f};
            #pragma unroll
            for (int nt = 0; nt < 4; ++nt) {
                acc[nt] = __builtin_amdgcn_mfma_f32_16x16x32_bf16(a0, bfrag[0][nt], acc[nt], 0, 0, 0);
                acc[nt] = __builtin_amdgcn_mfma_f32_16x16x32_bf16(a1, bfrag[1][nt], acc[nt], 0, 0, 0);
            }

            // Scatter D into LDS. D row r of quad q == slot base + q*4 + r,
            // whose record lives in lane q*4+r (0..15). XOR-bit4 swizzle on
            // row parity breaks the 4-quad same-bank pattern.
            #pragma unroll
            for (int r = 0; r < 4; ++r) {
                const int rec_r = __shfl(rec, q * 4 + r);
                if (q * 4 + r < rem) {
                    const int loc = rec_r >> 18;
                    const int sw  = (loc & 1) << 4;
                    #pragma unroll
                    for (int nt = 0; nt < 4; ++nt) {
                        const int c = nt * 16 + m;
                        lds_add_f32(lds_base + (unsigned)((loc * COUT + (c ^ sw)) << 2),
                                    acc[nt][r]);
                    }
                }
            }
        }
    }

    // Drain this wave's outstanding ds_add_f32 before the barrier, then sync.
    asm volatile("s_waitcnt lgkmcnt(0)" ::: "memory");
    __syncthreads();

    // Fused BN + ReLU epilogue: thread t -> row loc = t>>1, cols [(t&1)*32, +32).
    const int loc = tid >> 1;
    const int c0  = (tid & 1) * 32;
    const int gr  = b * RB + loc;
    if (gr < NPTS) {
        const int sw = (loc & 1) << 4;
        #pragma unroll
        for (int cc = 0; cc < 32; cc += 4) {
            const int c = c0 + cc;
            const f32x4 v = *(const f32x4*)(&sacc[loc * COUT + (c ^ sw)]);
            f32x4 o;
            #pragma unroll
            for (int e = 0; e < 4; ++e) {
                const float sc = gamma[c + e] * rsqrtf(rvar[c + e] + BN_EPS);
                const float bi = beta[c + e] - rmean[c + e] * sc;
                o[e] = fmaxf(v[e] * sc + bi, 0.f);
            }
            *(f32x4*)(out + (size_t)gr * COUT + c) = o;
        }
    }
}

// ---- launch -----------------------------------------------------------------
extern "C" void kernel_launch(void* const* d_in, const int* in_sizes, int n_in,
                              void* d_out, int out_size, void* d_ws, size_t ws_size,
                              hipStream_t stream) {
    const float* feats = (const float*)d_in[0];
    const float* wk    = (const float*)d_in[1];
    const float* gamma = (const float*)d_in[2];
    const float* beta  = (const float*)d_in[3];
    const float* rmean = (const float*)d_in[4];
    const float* rvar  = (const float*)d_in[5];
    const int* imap    = (const int*)d_in[6];
    const int* omap    = (const int*)d_in[7];
    float* out         = (float*)d_out;

    // Workspace carve-up (1 KB aligned), ~18 MB total.
    char* ws = (char*)d_ws;
    auto align1k = [](size_t x) { return (x + 1023) & ~(size_t)1023; };
    size_t p = 0;
    int* cnt8     = (int*)(ws + p); p += align1k((size_t)NSEG * NSUB * 4);
    int* cur8     = (int*)(ws + p); p += align1k((size_t)NSEG * NSUB * 4);
    int* off      = (int*)(ws + p); p += align1k(NSEG * 4);
    int* off8     = (int*)(ws + p); p += align1k((size_t)NSEG * NSUB * 4);
    int* cnt_tot  = (int*)(ws + p); p += align1k(NSEG * 4);
    int* bsum     = (int*)(ws + p); p += align1k(256 * 4);
    ushort* wpack = (ushort*)(ws + p); p += align1k((size_t)KVOL * 8 * 64 * 8 * 2);
    int* list     = (int*)(ws + p); p += align1k((size_t)LIST_CAP * 4);

    // cnt8 and cur8 are contiguous: one memset zeroes both.
    hipMemsetAsync(cnt8, 0, align1k((size_t)NSEG * NSUB * 4) + (size_t)NSEG * NSUB * 4, stream);

    const int pb = (NTOT + 255) / 256;
    hist_kernel<<<pb, 256, 0, stream>>>(omap, cnt8);
    scan_block_kernel<<<SCAN_BLOCKS, 256, 0, stream>>>(cnt8, off, cnt_tot, bsum);
    scan_bsum_kernel<<<1, 256, 0, stream>>>(bsum);
    add_offsets_kernel<<<SCAN_BLOCKS, 256, 0, stream>>>(off, bsum, cnt8, off8);
    fill_kernel<<<pb, 256, 0, stream>>>(imap, omap, off8, cur8, list);
    repack_w_kernel<<<(KVOL * 8 * 64 * 8 + 255) / 256, 256, 0, stream>>>(wk, wpack);

    conv_bucket_kernel<<<NB, 256, 0, stream>>>(
        feats, wpack, off, cnt_tot, list, gamma, beta, rmean, rvar, out);
}

// Round 7
// 1244.377 us; speedup vs baseline: 1.9499x; 1.1406x over previous
//
#include <hip/hip_runtime.h>
#include <hip/hip_bf16.h>
#include <hip/hip_fp16.h>

#define NPTS 200000
#define CIN 64
#define COUT 64
#define KVOL 27
#define NPAIRS 100000
#define GROUPS_PER_K (NPAIRS / 16)                                               // 6250
#define GROUPS_PER_BLOCK 64
#define CHUNKS_PER_K ((GROUPS_PER_K + GROUPS_PER_BLOCK - 1) / GROUPS_PER_BLOCK)  // 98
#define BN_EPS 1e-5f

typedef __attribute__((ext_vector_type(8))) short short8;   // 8 bf16 bits (4 VGPRs)
typedef __attribute__((ext_vector_type(4))) float f32x4;
typedef _Float16 __attribute__((ext_vector_type(2))) h16x2;

__device__ inline ushort f2bf(float x) {
    union { __hip_bfloat16 h; ushort u; } cv;
    cv.h = __float2bfloat16(x);   // RNE
    return cv.u;
}

// Packed 2xf16 atomic add via the GLOBAL encoding (addrspace 1).
// 4 B payload per op, 2 elements -> halves both atomic bytes AND ops vs
// scalar f32 (R2/R4's wall: ~1.2 TB/s memory-side atomic drain, ~307 Gops).
// NOT the flat path (R5's flat pk op measured 32 B/op memory-side).
__device__ __forceinline__ void atomic_pk_add_f16(__half* addr, float lo, float hi) {
    h16x2 v = { (_Float16)lo, (_Float16)hi };   // RNE converts
#if __has_builtin(__builtin_amdgcn_global_atomic_fadd_v2f16)
    typedef h16x2 __attribute__((address_space(1))) gh16x2;
    __builtin_amdgcn_global_atomic_fadd_v2f16((gh16x2*)(unsigned long long)addr, v);
#else
    union { h16x2 h; unsigned u; } cv; cv.h = v;
    asm volatile("global_atomic_pk_add_f16 %0, %1, off"
                 :: "v"((void*)addr), "v"(cv.u) : "memory");
#endif
}

// Per 16-pair group, one wave computes contrib^T[64 couts][16 pairs] via 8 MFMAs
// with swapped operands (A = W^T tile, B = feats^T), so each lane holds
// 4 CONSECUTIVE couts of ONE pair per nt-tile -> 2 packed f16 atomics per tile.
//  A[m=lane&15][k=q*8+e] = W[k][cout=nt*16+m]
//  B[k=q*8+e][j=lane&15] = feats[row_j][k]
//  D[row=cout_local=q*4+r][col=pair=m]   (HW-verified in R5: absmax passed)
__global__ __launch_bounds__(256) void conv_scatter_kernel(
    const float* __restrict__ feats,      // fp32 [NPTS][CIN]
    const float* __restrict__ wk,         // fp32 [KVOL][CIN][COUT]
    const int* __restrict__ in_map,       // [KVOL][NPAIRS]
    const int* __restrict__ out_map,      // [KVOL][NPAIRS]
    __half* __restrict__ accum)           // [NPTS][COUT] f16
{
    const int koff  = blockIdx.x / CHUNKS_PER_K;
    const int chunk = blockIdx.x % CHUNKS_PER_K;
    const int lane  = threadIdx.x & 63;
    const int wave  = threadIdx.x >> 6;
    const int m     = lane & 15;
    const int q     = lane >> 4;

    // W[koff] fragments (fp32 -> bf16), once per block (amortized over 64 groups).
    short8 wfrag[2][4];
    const float* wbase = wk + koff * (CIN * COUT);
    #pragma unroll
    for (int h = 0; h < 2; ++h) {
        #pragma unroll
        for (int nt = 0; nt < 4; ++nt) {
            #pragma unroll
            for (int e = 0; e < 8; ++e) {
                const int kin = h * 32 + q * 8 + e;
                wfrag[h][nt][e] = (short)f2bf(wbase[kin * COUT + nt * 16 + m]);
            }
        }
    }

    const int* imap = in_map + koff * NPAIRS;
    const int* omap = out_map + koff * NPAIRS;

    #pragma unroll 1
    for (int it = 0; it < GROUPS_PER_BLOCK / 4; ++it) {
        const int g = chunk * GROUPS_PER_BLOCK + it * 4 + wave;
        if (g >= GROUPS_PER_K) break;
        const int base = g * 16;

        // Gather B-operand: lane m owns pair m's input row.
        const int row = imap[base + m];
        const float* fr = feats + (size_t)row * CIN + q * 8;
        const f32x4 f00 = *(const f32x4*)(fr);
        const f32x4 f01 = *(const f32x4*)(fr + 4);
        const f32x4 f10 = *(const f32x4*)(fr + 32);
        const f32x4 f11 = *(const f32x4*)(fr + 36);

        short8 b0, b1;
        #pragma unroll
        for (int e = 0; e < 4; ++e) {
            b0[e]     = (short)f2bf(f00[e]);
            b0[e + 4] = (short)f2bf(f01[e]);
            b1[e]     = (short)f2bf(f10[e]);
            b1[e + 4] = (short)f2bf(f11[e]);
        }

        f32x4 acc[4];
        #pragma unroll
        for (int nt = 0; nt < 4; ++nt) acc[nt] = (f32x4){0.f, 0.f, 0.f, 0.f};
        #pragma unroll
        for (int nt = 0; nt < 4; ++nt) {
            acc[nt] = __builtin_amdgcn_mfma_f32_16x16x32_bf16(wfrag[0][nt], b0, acc[nt], 0, 0, 0);
            acc[nt] = __builtin_amdgcn_mfma_f32_16x16x32_bf16(wfrag[1][nt], b1, acc[nt], 0, 0, 0);
        }

        // Scatter: lane (q,m) holds couts nt*16 + q*4 + [0..3] of pair m.
        const int orow = omap[base + m];
        __half* obase = accum + (size_t)orow * COUT + q * 4;
        #pragma unroll
        for (int nt = 0; nt < 4; ++nt) {
            atomic_pk_add_f16(obase + nt * 16,     acc[nt][0], acc[nt][1]);
            atomic_pk_add_f16(obase + nt * 16 + 2, acc[nt][2], acc[nt][3]);
        }
    }
}

// BN (inference-folded) + ReLU; f16 accum -> fp32 out. 8 elems/thread.
__global__ __launch_bounds__(256) void bn_relu_kernel(
    const __half* __restrict__ accum,
    const float* __restrict__ gamma,
    const float* __restrict__ beta,
    const float* __restrict__ rmean,
    const float* __restrict__ rvar,
    float* __restrict__ out)
{
    __shared__ float s_scale[COUT];
    __shared__ float s_bias[COUT];
    if (threadIdx.x < COUT) {
        const int c = threadIdx.x;
        const float sc = gamma[c] * rsqrtf(rvar[c] + BN_EPS);
        s_scale[c] = sc;
        s_bias[c]  = beta[c] - rmean[c] * sc;
    }
    __syncthreads();

    const int idx = (blockIdx.x * 256 + threadIdx.x) * 8;
    if (idx < NPTS * COUT) {
        const int c0 = idx & (COUT - 1);   // 8 | COUT: stays in one row
        union { ushort4 u4; __half h[8]; } in2;
        const ushort4* src = (const ushort4*)(accum + idx);
        in2.u4 = src[0];
        union { ushort4 u4b; __half h[8]; } dummy;  // (unused; keep simple below)
        // load all 8 halves via two ushort4 loads
        ushort4 raw0 = ((const ushort4*)(accum + idx))[0];
        ushort4 raw1 = ((const ushort4*)(accum + idx))[1];
        const __half* h0 = (const __half*)&raw0;
        const __half* h1 = (const __half*)&raw1;
        f32x4 o0, o1;
        #pragma unroll
        for (int e = 0; e < 4; ++e) {
            o0[e] = fmaxf(__half2float(h0[e]) * s_scale[c0 + e]     + s_bias[c0 + e],     0.f);
            o1[e] = fmaxf(__half2float(h1[e]) * s_scale[c0 + 4 + e] + s_bias[c0 + 4 + e], 0.f);
        }
        *(f32x4*)(out + idx)     = o0;
        *(f32x4*)(out + idx + 4) = o1;
    }
}

extern "C" void kernel_launch(void* const* d_in, const int* in_sizes, int n_in,
                              void* d_out, int out_size, void* d_ws, size_t ws_size,
                              hipStream_t stream) {
    const float* feats = (const float*)d_in[0];
    const float* wk    = (const float*)d_in[1];
    const float* gamma = (const float*)d_in[2];
    const float* beta  = (const float*)d_in[3];
    const float* rmean = (const float*)d_in[4];
    const float* rvar  = (const float*)d_in[5];
    const int* imap    = (const int*)d_in[6];
    const int* omap    = (const int*)d_in[7];
    float* out         = (float*)d_out;
    __half* accum      = (__half*)d_ws;   // 200000*64*2 = 25.6 MB scratch

    hipMemsetAsync(accum, 0, (size_t)NPTS * COUT * sizeof(__half), stream);

    conv_scatter_kernel<<<KVOL * CHUNKS_PER_K, 256, 0, stream>>>(feats, wk, imap, omap, accum);

    bn_relu_kernel<<<(NPTS * COUT / 8 + 255) / 256, 256, 0, stream>>>(
        accum, gamma, beta, rmean, rvar, out);
}

// Round 8
// 1147.065 us; speedup vs baseline: 2.1153x; 1.0848x over previous
//
#include <hip/hip_runtime.h>
#include <hip/hip_bf16.h>

#define NPTS 200000
#define CIN 64
#define COUT 64
#define KVOL 27
#define NPAIRS 100000
#define NTOT (KVOL * NPAIRS)                                                     // 2.7M
#define GROUPS_PER_K (NPAIRS / 16)                                               // 6250
#define GROUPS_PER_BLOCK 64
#define CHUNKS_PER_K ((GROUPS_PER_K + GROUPS_PER_BLOCK - 1) / GROUPS_PER_BLOCK)  // 98
#define PAIR_BLOCKS ((NTOT + 255) / 256)                                         // 10547
#define SCAN_BLOCKS ((NPTS + 255) / 256)                                         // 782
#define RED_BLOCKS 1024
#define BN_EPS 1e-5f

typedef __attribute__((ext_vector_type(8))) short short8;   // 8 bf16 bits
typedef __attribute__((ext_vector_type(4))) float f32x4;

__device__ inline ushort f2bf(float x) {
    union { __hip_bfloat16 h; ushort u; } cv;
    cv.h = __float2bfloat16(x);   // RNE
    return cv.u;
}
__device__ inline float bf2f(ushort v) {
    union { unsigned u; float f; } cv; cv.u = ((unsigned)v) << 16; return cv.f;
}

// ---- Phase A: counting sort of pair ids t (k = t/NPAIRS) by out row ---------

__global__ __launch_bounds__(256) void hist_kernel(
    const int* __restrict__ out_map, int* __restrict__ cnt)
{
    const int t = blockIdx.x * 256 + threadIdx.x;
    if (t < NTOT) atomicAdd(&cnt[out_map[t]], 1);
}

__global__ __launch_bounds__(256) void scan_block_kernel(
    const int* __restrict__ cnt, int* __restrict__ row_off, int* __restrict__ bsum)
{
    __shared__ int s[256];
    const int tid = threadIdx.x;
    const int idx = blockIdx.x * 256 + tid;
    const int v = (idx < NPTS) ? cnt[idx] : 0;
    s[tid] = v;
    __syncthreads();
    for (int d = 1; d < 256; d <<= 1) {
        const int t = (tid >= d) ? s[tid - d] : 0;
        __syncthreads();
        s[tid] += t;
        __syncthreads();
    }
    if (idx < NPTS) row_off[idx] = s[tid] - v;   // block-local exclusive
    if (tid == 255) bsum[blockIdx.x] = s[255];
}

__global__ __launch_bounds__(1024) void scan_bsum_kernel(int* __restrict__ bsum)
{
    __shared__ int s[1024];
    const int tid = threadIdx.x;
    const int v = (tid < SCAN_BLOCKS) ? bsum[tid] : 0;
    s[tid] = v;
    __syncthreads();
    for (int d = 1; d < 1024; d <<= 1) {
        const int t = (tid >= d) ? s[tid - d] : 0;
        __syncthreads();
        s[tid] += t;
        __syncthreads();
    }
    if (tid < SCAN_BLOCKS) bsum[tid] = s[tid] - v;  // exclusive
}

__global__ __launch_bounds__(256) void add_offsets_kernel(
    int* __restrict__ row_off, const int* __restrict__ bsum, int* __restrict__ cur)
{
    const int idx = blockIdx.x * 256 + threadIdx.x;
    if (idx < NPTS) {
        const int o = row_off[idx] + bsum[blockIdx.x];
        row_off[idx] = o;
        cur[idx] = o;
    }
    if (idx == 0) row_off[NPTS] = NTOT;   // sentinel
}

__global__ __launch_bounds__(256) void fill_kernel(
    const int* __restrict__ out_map, int* __restrict__ cur, int* __restrict__ entries)
{
    const int t = blockIdx.x * 256 + threadIdx.x;
    if (t < NTOT) {
        const int slot = atomicAdd(&cur[out_map[t]], 1);
        entries[slot] = t;
    }
}

// ---- Phase B: dense per-k gather+GEMM, contrib written bf16 (no scatter) ---
// Swapped-operand layout (HW-verified R5): D[row=cout_local=q*4+r][col=pair=m],
// so lane (q,m) holds couts nt*16+q*4+[0..3] of pair m -> 4 x 8B stores.
__global__ __launch_bounds__(256) void contrib_gemm_kernel(
    const float* __restrict__ feats,      // fp32 [NPTS][CIN]
    const float* __restrict__ wk,         // fp32 [KVOL][CIN][COUT]
    const int* __restrict__ in_map,       // [KVOL][NPAIRS]
    ushort* __restrict__ contrib,         // bf16 [kcount*NPAIRS][COUT]
    int kbase)
{
    const int klocal = blockIdx.x / CHUNKS_PER_K;
    const int koff   = kbase + klocal;
    const int chunk  = blockIdx.x % CHUNKS_PER_K;
    const int lane   = threadIdx.x & 63;
    const int wave   = threadIdx.x >> 6;
    const int m      = lane & 15;
    const int q      = lane >> 4;

    short8 wfrag[2][4];
    const float* wbase = wk + koff * (CIN * COUT);
    #pragma unroll
    for (int h = 0; h < 2; ++h)
        #pragma unroll
        for (int nt = 0; nt < 4; ++nt)
            #pragma unroll
            for (int e = 0; e < 8; ++e) {
                const int kin = h * 32 + q * 8 + e;
                wfrag[h][nt][e] = (short)f2bf(wbase[kin * COUT + nt * 16 + m]);
            }

    const int* imap = in_map + koff * NPAIRS;

    #pragma unroll 1
    for (int it = 0; it < GROUPS_PER_BLOCK / 4; ++it) {
        const int g = chunk * GROUPS_PER_BLOCK + it * 4 + wave;
        if (g >= GROUPS_PER_K) break;
        const int base = g * 16;

        const int row = imap[base + m];
        const float* fr = feats + (size_t)row * CIN + q * 8;
        const f32x4 f00 = *(const f32x4*)(fr);
        const f32x4 f01 = *(const f32x4*)(fr + 4);
        const f32x4 f10 = *(const f32x4*)(fr + 32);
        const f32x4 f11 = *(const f32x4*)(fr + 36);

        short8 b0, b1;
        #pragma unroll
        for (int e = 0; e < 4; ++e) {
            b0[e]     = (short)f2bf(f00[e]);
            b0[e + 4] = (short)f2bf(f01[e]);
            b1[e]     = (short)f2bf(f10[e]);
            b1[e + 4] = (short)f2bf(f11[e]);
        }

        f32x4 acc[4];
        #pragma unroll
        for (int nt = 0; nt < 4; ++nt) acc[nt] = (f32x4){0.f, 0.f, 0.f, 0.f};
        #pragma unroll
        for (int nt = 0; nt < 4; ++nt) {
            acc[nt] = __builtin_amdgcn_mfma_f32_16x16x32_bf16(wfrag[0][nt], b0, acc[nt], 0, 0, 0);
            acc[nt] = __builtin_amdgcn_mfma_f32_16x16x32_bf16(wfrag[1][nt], b1, acc[nt], 0, 0, 0);
        }

        ushort* crow = contrib + (((size_t)klocal * NPAIRS + base + m) << 6) + q * 4;
        #pragma unroll
        for (int nt = 0; nt < 4; ++nt) {
            ushort4 st;
            st.x = f2bf(acc[nt][0]); st.y = f2bf(acc[nt][1]);
            st.z = f2bf(acc[nt][2]); st.w = f2bf(acc[nt][3]);
            *(ushort4*)(crow + nt * 16) = st;
        }
    }
}

// ---- Phase C: per-row gather-reduce + fused BN/ReLU (no atomics) -----------
// One wave per out row; lane = cout. Entries batched 64-wide, broadcast via
// readlane so contrib loads (coalesced 128B each) issue independently.
__global__ __launch_bounds__(256) void reduce_kernel(
    const ushort* __restrict__ contrib,   // bf16 [kcount*NPAIRS][COUT]
    const int* __restrict__ entries,      // [NTOT] pair ids sorted by out row
    const int* __restrict__ row_off,      // [NPTS+1]
    float* __restrict__ accum,            // fp32 [NPTS][COUT] (multi-chunk only)
    const float* __restrict__ gamma, const float* __restrict__ beta,
    const float* __restrict__ rmean, const float* __restrict__ rvar,
    float* __restrict__ out,
    int kbase, int kcount, int do_init, int do_bn)
{
    const int lane = threadIdx.x & 63;
    const int wid  = blockIdx.x * 4 + (threadIdx.x >> 6);

    const float sc = gamma[lane] * rsqrtf(rvar[lane] + BN_EPS);
    const float bi = beta[lane] - rmean[lane] * sc;

    #pragma unroll 1
    for (int row = wid; row < NPTS; row += RED_BLOCKS * 4) {
        const int s = row_off[row];
        const int e = row_off[row + 1];
        float a = do_init ? 0.f : accum[(size_t)row * COUT + lane];

        #pragma unroll 1
        for (int b = s; b < e; b += 64) {
            const int nb = (e - b < 64) ? (e - b) : 64;
            const int ent = (lane < nb) ? entries[b + lane] : 0;
            #pragma unroll 1
            for (int i = 0; i < nb; ++i) {
                const int et = __builtin_amdgcn_readlane(ent, i);
                const int k = et / NPAIRS;
                if ((unsigned)(k - kbase) < (unsigned)kcount) {
                    const int pid = et - k * NPAIRS;
                    const ushort v =
                        contrib[(((size_t)(k - kbase) * NPAIRS + pid) << 6) + lane];
                    a += bf2f(v);
                }
            }
        }

        if (do_bn) out[(size_t)row * COUT + lane] = fmaxf(a * sc + bi, 0.f);
        else       accum[(size_t)row * COUT + lane] = a;
    }
}

// ---- Fallback (tiny workspace): proven R4 flat-scatter path ----------------
__global__ __launch_bounds__(256) void fb_conv_scatter(
    const float* __restrict__ feats, const float* __restrict__ wk,
    const int* __restrict__ in_map, const int* __restrict__ out_map,
    float* __restrict__ accum)
{
    const int koff  = blockIdx.x / CHUNKS_PER_K;
    const int chunk = blockIdx.x % CHUNKS_PER_K;
    const int lane  = threadIdx.x & 63;
    const int wave  = threadIdx.x >> 6;
    const int m = lane & 15, q = lane >> 4;
    short8 wfrag[2][4];
    const float* wbase = wk + koff * (CIN * COUT);
    #pragma unroll
    for (int h = 0; h < 2; ++h)
        #pragma unroll
        for (int nt = 0; nt < 4; ++nt)
            #pragma unroll
            for (int e = 0; e < 8; ++e)
                wfrag[h][nt][e] = (short)f2bf(wbase[(h*32 + q*8 + e) * COUT + nt*16 + m]);
    const int* imap = in_map + koff * NPAIRS;
    const int* omap = out_map + koff * NPAIRS;
    #pragma unroll 1
    for (int it = 0; it < GROUPS_PER_BLOCK / 4; ++it) {
        const int g = chunk * GROUPS_PER_BLOCK + it * 4 + wave;
        if (g >= GROUPS_PER_K) break;
        const int base = g * 16;
        const int row = imap[base + m];
        const float* fr = feats + (size_t)row * CIN + q * 8;
        const f32x4 f00 = *(const f32x4*)(fr);
        const f32x4 f01 = *(const f32x4*)(fr + 4);
        const f32x4 f10 = *(const f32x4*)(fr + 32);
        const f32x4 f11 = *(const f32x4*)(fr + 36);
        short8 b0, b1;
        #pragma unroll
        for (int e = 0; e < 4; ++e) {
            b0[e] = (short)f2bf(f00[e]); b0[e+4] = (short)f2bf(f01[e]);
            b1[e] = (short)f2bf(f10[e]); b1[e+4] = (short)f2bf(f11[e]);
        }
        f32x4 acc[4];
        #pragma unroll
        for (int nt = 0; nt < 4; ++nt) acc[nt] = (f32x4){0.f,0.f,0.f,0.f};
        #pragma unroll
        for (int nt = 0; nt < 4; ++nt) {
            acc[nt] = __builtin_amdgcn_mfma_f32_16x16x32_bf16(wfrag[0][nt], b0, acc[nt], 0,0,0);
            acc[nt] = __builtin_amdgcn_mfma_f32_16x16x32_bf16(wfrag[1][nt], b1, acc[nt], 0,0,0);
        }
        const int orow = omap[base + m];
        float* obase = accum + (size_t)orow * COUT + q * 4;
        #pragma unroll
        for (int nt = 0; nt < 4; ++nt)
            #pragma unroll
            for (int r = 0; r < 4; ++r)
                atomicAdd(obase + nt * 16 + r, acc[nt][r]);
    }
}

__global__ __launch_bounds__(256) void fb_bn_relu(
    const float* __restrict__ accum,
    const float* __restrict__ gamma, const float* __restrict__ beta,
    const float* __restrict__ rmean, const float* __restrict__ rvar,
    float* __restrict__ out)
{
    const int idx = (blockIdx.x * 256 + threadIdx.x) * 4;
    if (idx < NPTS * COUT) {
        const f32x4 v = *(const f32x4*)(accum + idx);
        const int c0 = idx & (COUT - 1);
        f32x4 o;
        #pragma unroll
        for (int e = 0; e < 4; ++e) {
            const float sc = gamma[c0+e] * rsqrtf(rvar[c0+e] + BN_EPS);
            o[e] = fmaxf(v[e] * sc + (beta[c0+e] - rmean[c0+e] * sc), 0.f);
        }
        *(f32x4*)(out + idx) = o;
    }
}

// ---- launch -----------------------------------------------------------------
extern "C" void kernel_launch(void* const* d_in, const int* in_sizes, int n_in,
                              void* d_out, int out_size, void* d_ws, size_t ws_size,
                              hipStream_t stream) {
    const float* feats = (const float*)d_in[0];
    const float* wk    = (const float*)d_in[1];
    const float* gamma = (const float*)d_in[2];
    const float* beta  = (const float*)d_in[3];
    const float* rmean = (const float*)d_in[4];
    const float* rvar  = (const float*)d_in[5];
    const int* imap    = (const int*)d_in[6];
    const int* omap    = (const int*)d_in[7];
    float* out         = (float*)d_out;

    char* ws = (char*)d_ws;
    auto al = [](size_t x) { return (x + 1023) & ~(size_t)1023; };

    size_t p = 0;
    int* cnt     = (int*)(ws + p); p += al((size_t)NPTS * 4);
    int* row_off = (int*)(ws + p); p += al(((size_t)NPTS + 1) * 4);
    int* cur     = (int*)(ws + p); p += al((size_t)NPTS * 4);
    int* bsum    = (int*)(ws + p); p += al(1024 * 4);
    int* entries = (int*)(ws + p); p += al((size_t)NTOT * 4);
    const size_t fixed = p;
    const size_t CH = (size_t)NPAIRS * COUT * 2;       // 12.8 MB per k-slice
    const size_t ACC = (size_t)NPTS * COUT * 4;        // 51.2 MB

    int KC = 0;
    if (ws_size >= fixed + (size_t)KVOL * CH) {
        KC = KVOL;                                     // single chunk, no accum
    } else if (ws_size > fixed + ACC + CH) {
        KC = (int)((ws_size - fixed - ACC) / CH);
        if (KC > KVOL) KC = KVOL;
    }

    if (KC < 1) {
        // Fallback: proven flat-scatter (atomic-rate bound, correct).
        float* accum = (float*)d_ws;
        hipMemsetAsync(accum, 0, ACC, stream);
        fb_conv_scatter<<<KVOL * CHUNKS_PER_K, 256, 0, stream>>>(feats, wk, imap, omap, accum);
        fb_bn_relu<<<(NPTS * COUT / 4 + 255) / 256, 256, 0, stream>>>(
            accum, gamma, beta, rmean, rvar, out);
        return;
    }

    ushort* contrib = (ushort*)(ws + p); p += al((size_t)KC * CH);
    float* accum    = (KC < KVOL) ? (float*)(ws + p) : (float*)nullptr;

    // Phase A: counting sort of pair ids by out row.
    hipMemsetAsync(cnt, 0, (size_t)NPTS * 4, stream);
    hist_kernel<<<PAIR_BLOCKS, 256, 0, stream>>>(omap, cnt);
    scan_block_kernel<<<SCAN_BLOCKS, 256, 0, stream>>>(cnt, row_off, bsum);
    scan_bsum_kernel<<<1, 1024, 0, stream>>>(bsum);
    add_offsets_kernel<<<SCAN_BLOCKS, 256, 0, stream>>>(row_off, bsum, cur);
    fill_kernel<<<PAIR_BLOCKS, 256, 0, stream>>>(omap, cur, entries);

    // Phases B+C per k-chunk.
    for (int kbase = 0; kbase < KVOL; kbase += KC) {
        const int kc = (KVOL - kbase < KC) ? (KVOL - kbase) : KC;
        contrib_gemm_kernel<<<kc * CHUNKS_PER_K, 256, 0, stream>>>(
            feats, wk, imap, contrib, kbase);
        reduce_kernel<<<RED_BLOCKS, 256, 0, stream>>>(
            contrib, entries, row_off, accum, gamma, beta, rmean, rvar, out,
            kbase, kc, kbase == 0 ? 1 : 0, (kbase + kc >= KVOL) ? 1 : 0);
    }
}